// Round 1
// baseline (610.569 us; speedup 1.0000x reference)
//
#include <hip/hip_runtime.h>
#include <hip/hip_bf16.h>
#include <stdint.h>

// Problem constants (K=4, OUT=4096, IN=4096, B=2, S=2048)
#define DIM_M 4096   // B*S rows of x
#define DIM_N 4096   // OUT
#define DIM_K 4096   // IN
#define NBASE 4
#define BASE_STRIDE (DIM_N * DIM_K)  // 16777216 elements per basis

typedef __bf16 bf16x8 __attribute__((ext_vector_type(8)));
typedef float floatx4 __attribute__((ext_vector_type(4)));

typedef const __attribute__((address_space(1))) void* gptr1;
typedef __attribute__((address_space(3))) void* lptr3;

__device__ __forceinline__ void async_copy16(const void* g, void* l) {
    // width=16 global->LDS DMA; LDS dest is wave-uniform base + lane*16
    __builtin_amdgcn_global_load_lds((gptr1)g, (lptr3)l, 16, 0, 0);
}

__device__ __forceinline__ unsigned short f2bf(float f) {
    uint32_t u = __float_as_uint(f);
    uint32_t r = (u + 0x7FFFu + ((u >> 16) & 1u)) >> 16;  // RNE
    return (unsigned short)r;
}

// ---------------------------------------------------------------------------
// Prologue 1: W_bf16[n][i] = bf16( sum_k alphas[k] * bases[k][n][i] )
// bases delivered as int32 per harness contract ("integer -> const int*")
// ---------------------------------------------------------------------------
__global__ __launch_bounds__(256) void build_w_kernel(
        const int* __restrict__ bases, const float* __restrict__ alphas,
        unsigned short* __restrict__ Wb) {
    const long e = ((long)blockIdx.x * 256 + threadIdx.x) * 4;  // 4 elems/thread
    const float a0 = alphas[0], a1 = alphas[1], a2 = alphas[2], a3 = alphas[3];
    const int4 b0 = *(const int4*)(bases + e);
    const int4 b1 = *(const int4*)(bases + BASE_STRIDE + e);
    const int4 b2 = *(const int4*)(bases + 2L * BASE_STRIDE + e);
    const int4 b3 = *(const int4*)(bases + 3L * BASE_STRIDE + e);
    ushort4 o;
    o.x = f2bf(a0 * b0.x + a1 * b1.x + a2 * b2.x + a3 * b3.x);
    o.y = f2bf(a0 * b0.y + a1 * b1.y + a2 * b2.y + a3 * b3.y);
    o.z = f2bf(a0 * b0.z + a1 * b1.z + a2 * b2.z + a3 * b3.z);
    o.w = f2bf(a0 * b0.w + a1 * b1.w + a2 * b2.w + a3 * b3.w);
    *(ushort4*)(Wb + e) = o;
}

// ---------------------------------------------------------------------------
// Prologue 2: x fp32 -> bf16
// ---------------------------------------------------------------------------
__global__ __launch_bounds__(256) void convert_x_kernel(
        const float* __restrict__ x, unsigned short* __restrict__ Xb) {
    const long e = ((long)blockIdx.x * 256 + threadIdx.x) * 4;
    const float4 v = *(const float4*)(x + e);
    ushort4 o;
    o.x = f2bf(v.x); o.y = f2bf(v.y); o.z = f2bf(v.z); o.w = f2bf(v.w);
    *(ushort4*)(Xb + e) = o;
}

// ---------------------------------------------------------------------------
// Main GEMM: C[m][n] = sum_k A[m][k] * Bt[n][k]   (A=Xbf16, Bt=Wbf16)
// 128x128 block tile, 256 threads (4 waves in 2x2), BK=32,
// 16x16x32 bf16 MFMA, 4x4 accumulators per wave (64x64/wave),
// global_load_lds width-16 staging. m97-structure.
// ---------------------------------------------------------------------------
__global__ __launch_bounds__(256) void gemm_bt_kernel(
        const unsigned short* __restrict__ A, const unsigned short* __restrict__ Bt,
        float* __restrict__ C) {
    __shared__ unsigned short sA[128 * 32];
    __shared__ unsigned short sB[128 * 32];

    const int t = threadIdx.x;
    const int wave = t >> 6, lane = t & 63;
    const int wm = (wave >> 1) * 64;   // wave row offset in tile
    const int wn = (wave & 1) * 64;    // wave col offset in tile
    const int quad = lane >> 4, l16 = lane & 15;

    const int mBase = blockIdx.y * 128;
    const int nBase = blockIdx.x * 128;

    // Staging: row-major [128][32] tiles. Thread t covers elements t*8..t*8+7
    // (p=0) and 2048+t*8.. (p=1). Per wave: LDS dst = uniform base + lane*16. OK.
    const int srow = t >> 2;           // 0..63
    const int scol = (t & 3) * 8;      // 0,8,16,24
    const unsigned short* gA0 = A + (size_t)(mBase + srow) * DIM_K + scol;
    const unsigned short* gA1 = gA0 + (size_t)64 * DIM_K;
    const unsigned short* gB0 = Bt + (size_t)(nBase + srow) * DIM_K + scol;
    const unsigned short* gB1 = gB0 + (size_t)64 * DIM_K;
    unsigned short* lA0 = sA + t * 8;
    unsigned short* lA1 = sA + 2048 + t * 8;
    unsigned short* lB0 = sB + t * 8;
    unsigned short* lB1 = sB + 2048 + t * 8;

    // Fragment read offsets (elements) into [128][32] tiles
    const int aoff0 = (wm + l16) * 32 + quad * 8;
    const int boff0 = (wn + l16) * 32 + quad * 8;

    floatx4 acc[4][4] = {};

    for (int kt = 0; kt < DIM_K; kt += 32) {
        async_copy16(gA0, lA0);
        async_copy16(gA1, lA1);
        async_copy16(gB0, lB0);
        async_copy16(gB1, lB1);
        gA0 += 32; gA1 += 32; gB0 += 32; gB1 += 32;
        __syncthreads();  // drains vmcnt(0): staged tile visible

        bf16x8 a[4], b[4];
#pragma unroll
        for (int i = 0; i < 4; i++)
            a[i] = *(const bf16x8*)(sA + aoff0 + i * 16 * 32);
#pragma unroll
        for (int j = 0; j < 4; j++)
            b[j] = *(const bf16x8*)(sB + boff0 + j * 16 * 32);

#pragma unroll
        for (int i = 0; i < 4; i++)
#pragma unroll
            for (int j = 0; j < 4; j++)
                acc[i][j] = __builtin_amdgcn_mfma_f32_16x16x32_bf16(
                    a[i], b[j], acc[i][j], 0, 0, 0);

        __syncthreads();  // protect sA/sB before next stage
    }

    // Epilogue: C/D layout col=lane&15, row=quad*4+reg  [measured m89/m91]
#pragma unroll
    for (int i = 0; i < 4; i++) {
#pragma unroll
        for (int j = 0; j < 4; j++) {
#pragma unroll
            for (int r = 0; r < 4; r++) {
                const int row = mBase + wm + i * 16 + quad * 4 + r;
                const int col = nBase + wn + j * 16 + l16;
                C[(size_t)row * DIM_N + col] = acc[i][j][r];
            }
        }
    }
}

// ---------------------------------------------------------------------------
// Fallback (only if workspace too small): direct fp32, one thread per output
// ---------------------------------------------------------------------------
__global__ __launch_bounds__(256) void naive_kernel(
        const float* __restrict__ x, const float* __restrict__ alphas,
        const int* __restrict__ bases, float* __restrict__ out) {
    const long o = (long)blockIdx.x * 256 + threadIdx.x;
    const int m = (int)(o >> 12), n = (int)(o & 4095);
    const float a0 = alphas[0], a1 = alphas[1], a2 = alphas[2], a3 = alphas[3];
    const float* xr = x + (long)m * DIM_K;
    const int* b0 = bases + (long)n * DIM_K;
    const int* b1 = b0 + BASE_STRIDE;
    const int* b2 = b1 + BASE_STRIDE;
    const int* b3 = b2 + BASE_STRIDE;
    float acc = 0.f;
    for (int i = 0; i < DIM_K; i++) {
        float w = a0 * b0[i] + a1 * b1[i] + a2 * b2[i] + a3 * b3[i];
        acc += xr[i] * w;
    }
    out[o] = acc;
}

extern "C" void kernel_launch(void* const* d_in, const int* in_sizes, int n_in,
                              void* d_out, int out_size, void* d_ws, size_t ws_size,
                              hipStream_t stream) {
    const float* x      = (const float*)d_in[0];
    const float* alphas = (const float*)d_in[1];
    const int*   bases  = (const int*)d_in[2];
    float* out = (float*)d_out;

    const size_t need = (size_t)2 * DIM_N * DIM_K + (size_t)2 * DIM_M * DIM_K; // 64 MB
    if (ws_size >= need) {
        unsigned short* Wb = (unsigned short*)d_ws;                    // [4096][4096] bf16
        unsigned short* Xb = (unsigned short*)d_ws + (size_t)DIM_N * DIM_K;
        build_w_kernel<<<DIM_N * DIM_K / (4 * 256), 256, 0, stream>>>(bases, alphas, Wb);
        convert_x_kernel<<<DIM_M * DIM_K / (4 * 256), 256, 0, stream>>>(x, Xb);
        gemm_bt_kernel<<<dim3(DIM_N / 128, DIM_M / 128), 256, 0, stream>>>(Xb, Wb, out);
    } else {
        naive_kernel<<<(DIM_M * DIM_N) / 256, 256, 0, stream>>>(x, alphas, bases, out);
    }
}

// Round 2
// 599.179 us; speedup vs baseline: 1.0190x; 1.0190x over previous
//
#include <hip/hip_runtime.h>
#include <hip/hip_bf16.h>
#include <stdint.h>

// Problem constants (K=4, OUT=4096, IN=4096, B=2, S=2048)
#define DIM_M 4096   // B*S rows of x
#define DIM_N 4096   // OUT
#define DIM_K 4096   // IN
#define NBASE 4
#define BASE_STRIDE (DIM_N * DIM_K)  // 16777216 elements per basis

typedef __bf16 bf16x8 __attribute__((ext_vector_type(8)));
typedef float floatx4 __attribute__((ext_vector_type(4)));
typedef unsigned short ushort8 __attribute__((ext_vector_type(8)));

typedef const __attribute__((address_space(1))) void* gptr1;
typedef __attribute__((address_space(3))) void* lptr3;

__device__ __forceinline__ void async_copy16(const void* g, void* l) {
    // width=16 global->LDS DMA; LDS dest is wave-uniform base + lane*16
    __builtin_amdgcn_global_load_lds((gptr1)g, (lptr3)l, 16, 0, 0);
}

__device__ __forceinline__ unsigned short f2bf(float f) {
    uint32_t u = __float_as_uint(f);
    uint32_t r = (u + 0x7FFFu + ((u >> 16) & 1u)) >> 16;  // RNE
    return (unsigned short)r;
}

// ---------------------------------------------------------------------------
// Fused prologue: blocks [0, 8192) build W_bf16 = bf16(sum_k alpha_k*bases_k);
// blocks [8192, 16384) convert x fp32 -> bf16. 8 elems/thread, 16B stores.
// ---------------------------------------------------------------------------
__global__ __launch_bounds__(256) void prep_kernel(
        const int* __restrict__ bases, const float* __restrict__ alphas,
        const float* __restrict__ x,
        unsigned short* __restrict__ Wb, unsigned short* __restrict__ Xb) {
    const int bid = blockIdx.x;
    if (bid < 8192) {
        const long e = ((long)bid * 256 + threadIdx.x) * 8;
        const float a0 = alphas[0], a1 = alphas[1], a2 = alphas[2], a3 = alphas[3];
        const int4 p0 = *(const int4*)(bases + e);
        const int4 p1 = *(const int4*)(bases + e + 4);
        const int4 q0 = *(const int4*)(bases + BASE_STRIDE + e);
        const int4 q1 = *(const int4*)(bases + BASE_STRIDE + e + 4);
        const int4 r0 = *(const int4*)(bases + 2L * BASE_STRIDE + e);
        const int4 r1 = *(const int4*)(bases + 2L * BASE_STRIDE + e + 4);
        const int4 s0 = *(const int4*)(bases + 3L * BASE_STRIDE + e);
        const int4 s1 = *(const int4*)(bases + 3L * BASE_STRIDE + e + 4);
        ushort8 o;
        o[0] = f2bf(a0 * p0.x + a1 * q0.x + a2 * r0.x + a3 * s0.x);
        o[1] = f2bf(a0 * p0.y + a1 * q0.y + a2 * r0.y + a3 * s0.y);
        o[2] = f2bf(a0 * p0.z + a1 * q0.z + a2 * r0.z + a3 * s0.z);
        o[3] = f2bf(a0 * p0.w + a1 * q0.w + a2 * r0.w + a3 * s0.w);
        o[4] = f2bf(a0 * p1.x + a1 * q1.x + a2 * r1.x + a3 * s1.x);
        o[5] = f2bf(a0 * p1.y + a1 * q1.y + a2 * r1.y + a3 * s1.y);
        o[6] = f2bf(a0 * p1.z + a1 * q1.z + a2 * r1.z + a3 * s1.z);
        o[7] = f2bf(a0 * p1.w + a1 * q1.w + a2 * r1.w + a3 * s1.w);
        *(ushort8*)(Wb + e) = o;
    } else {
        const long e = ((long)(bid - 8192) * 256 + threadIdx.x) * 8;
        const float4 v0 = *(const float4*)(x + e);
        const float4 v1 = *(const float4*)(x + e + 4);
        ushort8 o;
        o[0] = f2bf(v0.x); o[1] = f2bf(v0.y); o[2] = f2bf(v0.z); o[3] = f2bf(v0.w);
        o[4] = f2bf(v1.x); o[5] = f2bf(v1.y); o[6] = f2bf(v1.z); o[7] = f2bf(v1.w);
        *(ushort8*)(Xb + e) = o;
    }
}

// ---------------------------------------------------------------------------
// Main GEMM: C[m][n] = sum_k A[m][k] * Bt[n][k]   (A=Xbf16, Bt=Wbf16)
// 128x128 block tile, 256 threads (4 waves in 2x2), BK=32,
// 16x16x32 bf16 MFMA, 4x4 accumulators per wave.
//
// LDS layout is XOR-swizzled to kill the 8-way ds_read_b128 bank conflict:
//   slot(row, qc) = row*4 + (qc ^ ((row>>1)&3))      (slots are 16B chunks)
// global_load_lds forces LDS dst = base + lane*16, so the swizzle is applied
// by permuting the GLOBAL source chunk per lane (same 64B segments touched).
// Fragment reads then use swz = quad ^ ((l16>>1)&3) (lane-constant) -> 2-way
// bank aliasing only, which is free (m136).
// ---------------------------------------------------------------------------
__global__ __launch_bounds__(256) void gemm_bt_kernel(
        const unsigned short* __restrict__ A, const unsigned short* __restrict__ Bt,
        float* __restrict__ C) {
    __shared__ unsigned short sA[128 * 32];
    __shared__ unsigned short sB[128 * 32];

    const int t = threadIdx.x;
    const int wave = t >> 6, lane = t & 63;
    const int wm = (wave >> 1) * 64;   // wave row offset in tile
    const int wn = (wave & 1) * 64;    // wave col offset in tile
    const int quad = lane >> 4, l16 = lane & 15;

    const int mBase = blockIdx.y * 128;
    const int nBase = blockIdx.x * 128;

    // Staging: thread t fills LDS slot t (and slot 256+t), i.e. row=t>>2,
    // stored chunk t&3, which must hold logical chunk qc = (t&3)^((t>>3)&3).
    const int srow = t >> 2;                      // 0..63
    const int qc = (t & 3) ^ ((t >> 3) & 3);      // swizzled source chunk
    const unsigned short* gA0 = A + (size_t)(mBase + srow) * DIM_K + qc * 8;
    const unsigned short* gA1 = gA0 + (size_t)64 * DIM_K;
    const unsigned short* gB0 = Bt + (size_t)(nBase + srow) * DIM_K + qc * 8;
    const unsigned short* gB1 = gB0 + (size_t)64 * DIM_K;
    unsigned short* lA0 = sA + t * 8;
    unsigned short* lA1 = sA + 2048 + t * 8;
    unsigned short* lB0 = sB + t * 8;
    unsigned short* lB1 = sB + 2048 + t * 8;

    // Fragment read offsets: logical chunk = quad, stored at quad^((row>>1)&3);
    // (row>>1)&3 == (l16>>1)&3 for all i (wm, i*16 are multiples of 8).
    const int swz = quad ^ ((l16 >> 1) & 3);
    const int aoff0 = (wm + l16) * 32 + swz * 8;
    const int boff0 = (wn + l16) * 32 + swz * 8;

    floatx4 acc[4][4] = {};

    for (int kt = 0; kt < DIM_K; kt += 32) {
        async_copy16(gA0, lA0);
        async_copy16(gA1, lA1);
        async_copy16(gB0, lB0);
        async_copy16(gB1, lB1);
        gA0 += 32; gA1 += 32; gB0 += 32; gB1 += 32;
        __syncthreads();  // drains vmcnt(0): staged tile visible

        bf16x8 a[4], b[4];
#pragma unroll
        for (int i = 0; i < 4; i++)
            a[i] = *(const bf16x8*)(sA + aoff0 + i * 16 * 32);
#pragma unroll
        for (int j = 0; j < 4; j++)
            b[j] = *(const bf16x8*)(sB + boff0 + j * 16 * 32);

#pragma unroll
        for (int i = 0; i < 4; i++)
#pragma unroll
            for (int j = 0; j < 4; j++)
                acc[i][j] = __builtin_amdgcn_mfma_f32_16x16x32_bf16(
                    a[i], b[j], acc[i][j], 0, 0, 0);

        __syncthreads();  // protect sA/sB before next stage
    }

    // Epilogue: C/D layout col=lane&15, row=quad*4+reg  [measured m89/m91]
#pragma unroll
    for (int i = 0; i < 4; i++) {
#pragma unroll
        for (int j = 0; j < 4; j++) {
#pragma unroll
            for (int r = 0; r < 4; r++) {
                const int row = mBase + wm + i * 16 + quad * 4 + r;
                const int col = nBase + wn + j * 16 + l16;
                C[(size_t)row * DIM_N + col] = acc[i][j][r];
            }
        }
    }
}

// ---------------------------------------------------------------------------
// Fallback (only if workspace too small): direct fp32, one thread per output
// ---------------------------------------------------------------------------
__global__ __launch_bounds__(256) void naive_kernel(
        const float* __restrict__ x, const float* __restrict__ alphas,
        const int* __restrict__ bases, float* __restrict__ out) {
    const long o = (long)blockIdx.x * 256 + threadIdx.x;
    const int m = (int)(o >> 12), n = (int)(o & 4095);
    const float a0 = alphas[0], a1 = alphas[1], a2 = alphas[2], a3 = alphas[3];
    const float* xr = x + (long)m * DIM_K;
    const int* b0 = bases + (long)n * DIM_K;
    const int* b1 = b0 + BASE_STRIDE;
    const int* b2 = b1 + BASE_STRIDE;
    const int* b3 = b2 + BASE_STRIDE;
    float acc = 0.f;
    for (int i = 0; i < DIM_K; i++) {
        float w = a0 * b0[i] + a1 * b1[i] + a2 * b2[i] + a3 * b3[i];
        acc += xr[i] * w;
    }
    out[o] = acc;
}

extern "C" void kernel_launch(void* const* d_in, const int* in_sizes, int n_in,
                              void* d_out, int out_size, void* d_ws, size_t ws_size,
                              hipStream_t stream) {
    const float* x      = (const float*)d_in[0];
    const float* alphas = (const float*)d_in[1];
    const int*   bases  = (const int*)d_in[2];
    float* out = (float*)d_out;

    const size_t need = (size_t)2 * DIM_N * DIM_K + (size_t)2 * DIM_M * DIM_K; // 64 MB
    if (ws_size >= need) {
        unsigned short* Wb = (unsigned short*)d_ws;                    // [4096][4096] bf16
        unsigned short* Xb = (unsigned short*)d_ws + (size_t)DIM_N * DIM_K;
        prep_kernel<<<16384, 256, 0, stream>>>(bases, alphas, x, Wb, Xb);
        gemm_bt_kernel<<<dim3(DIM_N / 128, DIM_M / 128), 256, 0, stream>>>(Xb, Wb, out);
    } else {
        naive_kernel<<<(DIM_M * DIM_N) / 256, 256, 0, stream>>>(x, alphas, bases, out);
    }
}